// Round 9
// baseline (277.471 us; speedup 1.0000x reference)
//
#include <hip/hip_runtime.h>
#include <hip/hip_bf16.h>

// TriangleAttention: S=256, H=4, DH=32, D=128.  All tensors fp32; bf16
// intermediates.  Round-9: attn rewrite with swapped-operand score MFMA
// (S^T layout) -> vector bias loads, 4-shuffle softmax, b64 P writes,
// halved P_lds (34.3 KB total, 4 blocks/CU).  Other kernels as round 8.
#define S_DIM 256
#define D_DIM 128
#define H_DIM 4
#define NPOS  (S_DIM * S_DIM)   // 65536

typedef __attribute__((ext_vector_type(8))) short  short8;   // 8 bf16 (4 VGPRs)
typedef __attribute__((ext_vector_type(4))) short  s4b;      // 4 bf16 (2 VGPRs)
typedef __attribute__((ext_vector_type(4))) float  f32x4;

__device__ __forceinline__ float b2f(unsigned short u) {
    union { float f; unsigned int u32; } c; c.u32 = ((unsigned int)u) << 16; return c.f;
}
__device__ __forceinline__ unsigned short f2b(float f) {
    __hip_bfloat16 h = __float2bfloat16(f);   // RNE
    return *reinterpret_cast<unsigned short*>(&h);
}

// ---------------------------------------------------------------------------
// K1: LayerNorm (fp32) + triangle-bias projection + attn_mask fold.
// ---------------------------------------------------------------------------
__global__ __launch_bounds__(256) void ln_biasmask_kernel(
    const float* __restrict__ x, const float* __restrict__ mask,
    const float* __restrict__ lnw, const float* __restrict__ lnb,
    const float* __restrict__ Wb, float* __restrict__ bm)
{
    const int wave = threadIdx.x >> 6, lane = threadIdx.x & 63;
    const int p = blockIdx.x * 4 + wave;

    float2 v = ((const float2*)x)[p * 64 + lane];
    float s = v.x + v.y, ss = v.x * v.x + v.y * v.y;
    #pragma unroll
    for (int m = 1; m < 64; m <<= 1) { s += __shfl_xor(s, m); ss += __shfl_xor(ss, m); }
    float mean = s * (1.f / 128.f);
    float var  = ss * (1.f / 128.f) - mean * mean;
    float rstd = rsqrtf(var + 1e-5f);

    float xn0 = (v.x - mean) * rstd * lnw[lane * 2]     + lnb[lane * 2];
    float xn1 = (v.y - mean) * rstd * lnw[lane * 2 + 1] + lnb[lane * 2 + 1];

    float mval = mask[p];
    #pragma unroll
    for (int h = 0; h < H_DIM; h++) {
        float d = xn0 * Wb[h * 128 + lane * 2] + xn1 * Wb[h * 128 + lane * 2 + 1];
        #pragma unroll
        for (int m = 1; m < 64; m <<= 1) d += __shfl_xor(d, m);
        if (lane == 0) bm[(long)h * NPOS + p] = d + mval;
    }
}

// ---------------------------------------------------------------------------
// K2: projection GEMM with fused LayerNorm (MFMA).  As round 8.
// ---------------------------------------------------------------------------
__global__ __launch_bounds__(256) void proj_ln_kernel(
    const float* __restrict__ x,
    const float* __restrict__ lnw, const float* __restrict__ lnb,
    const float* __restrict__ Wq, const float* __restrict__ Wk,
    const float* __restrict__ Wv, const float* __restrict__ Wg,
    int p0, unsigned short* __restrict__ strip)
{
    __shared__ __align__(16) unsigned short A_lds[64 * 136];
    __shared__ __align__(16) unsigned short W_lds[128 * 136];
    const int tid = threadIdx.x;
    const int m0 = blockIdx.x * 64;
    const int gy = blockIdx.y;
    const float* W = (gy == 0) ? Wq : (gy == 1) ? Wk : (gy == 2) ? Wv : Wg;

    const int lr = tid >> 4, c8 = (tid & 15) * 8;
    #pragma unroll
    for (int i = 0; i < 4; i++) {
        int row = lr + i * 16;
        const float* src = x + (size_t)(p0 + m0 + row) * 128 + c8;
        float4 f0 = *(const float4*)(src);
        float4 f1 = *(const float4*)(src + 4);
        float s  = f0.x + f0.y + f0.z + f0.w + f1.x + f1.y + f1.z + f1.w;
        float ss = f0.x*f0.x + f0.y*f0.y + f0.z*f0.z + f0.w*f0.w
                 + f1.x*f1.x + f1.y*f1.y + f1.z*f1.z + f1.w*f1.w;
        #pragma unroll
        for (int m = 1; m < 16; m <<= 1) { s += __shfl_xor(s, m); ss += __shfl_xor(ss, m); }
        float mean = s * (1.f / 128.f);
        float var  = ss * (1.f / 128.f) - mean * mean;
        float rstd = rsqrtf(var + 1e-5f);
        float xv[8] = {f0.x, f0.y, f0.z, f0.w, f1.x, f1.y, f1.z, f1.w};
        unsigned short pk[8];
        #pragma unroll
        for (int j = 0; j < 8; j++)
            pk[j] = f2b((xv[j] - mean) * rstd * lnw[c8 + j] + lnb[c8 + j]);
        *(uint4*)(&A_lds[row * 136 + c8]) = *(const uint4*)pk;
    }
    #pragma unroll
    for (int i = 0; i < 8; i++) {
        int wr = lr + i * 16;
        const float* src = W + (size_t)wr * 128 + c8;
        float4 f0 = *(const float4*)(src);
        float4 f1 = *(const float4*)(src + 4);
        unsigned short pk[8] = {f2b(f0.x), f2b(f0.y), f2b(f0.z), f2b(f0.w),
                                f2b(f1.x), f2b(f1.y), f2b(f1.z), f2b(f1.w)};
        *(uint4*)(&W_lds[wr * 136 + c8]) = *(const uint4*)pk;
    }
    __syncthreads();

    const int w = tid >> 6, lane = tid & 63;
    const int l16 = lane & 15, quad = lane >> 4;
    f32x4 acc[8];
    #pragma unroll
    for (int nt = 0; nt < 8; nt++) acc[nt] = (f32x4){0.f, 0.f, 0.f, 0.f};

    #pragma unroll
    for (int k0 = 0; k0 < 128; k0 += 32) {
        short8 a = *(const short8*)(&A_lds[(w * 16 + l16) * 136 + k0 + quad * 8]);
        #pragma unroll
        for (int nt = 0; nt < 8; nt++) {
            short8 b = *(const short8*)(&W_lds[(nt * 16 + l16) * 136 + k0 + quad * 8]);
            acc[nt] = __builtin_amdgcn_mfma_f32_16x16x32_bf16(a, b, acc[nt], 0, 0, 0);
        }
    }

    #pragma unroll
    for (int nt = 0; nt < 8; nt++)
        #pragma unroll
        for (int rr = 0; rr < 4; rr++) {
            int row = m0 + w * 16 + quad * 4 + rr;
            strip[(size_t)row * 512 + gy * 128 + nt * 16 + l16] = f2b(acc[nt][rr]);
        }
}

// ---------------------------------------------------------------------------
// K3: attention (MFMA), S^T score layout.  Block = (b, h); 4 waves x 4 q-tiles.
// Scores: mfma(A=K-frag, B=Q-frag) -> lane holds S[q=l16][key=nt*16+quad*4+rr].
// Softmax: per-lane over 64 keys + shfl_xor(16,32); 1/l folded into P.
// P -> per-wave LDS [16 q][136] (b64 writes, half the keys at a time) ->
// A-frags for PV.  Epilogue: sigmoid(g) gate, fp32 out.
// ---------------------------------------------------------------------------
__global__ __launch_bounds__(256, 4) void attn_kernel(
    const unsigned short* __restrict__ strip, const float* __restrict__ bm,
    int b0, float* __restrict__ out)
{
    __shared__ __align__(16) unsigned short VT_lds[32 * 264];     // V^T [dh][key]
    __shared__ __align__(16) unsigned short P_lds[4][16 * 136];   // per-wave P half
    const int bl = blockIdx.x, h = blockIdx.y;
    const int b  = b0 + bl;
    const int tid = threadIdx.x;

    {   // stage V^T
        const int row = tid >> 2, chunk = (tid & 3) * 8;
        #pragma unroll
        for (int i = 0; i < 4; i++) {
            int rr = row + i * 64;
            uint4 v = *(const uint4*)(strip + (size_t)(bl * 256 + rr) * 512 + 256 + h * 32 + chunk);
            unsigned short vs[8] = {
                (unsigned short)(v.x & 0xffff), (unsigned short)(v.x >> 16),
                (unsigned short)(v.y & 0xffff), (unsigned short)(v.y >> 16),
                (unsigned short)(v.z & 0xffff), (unsigned short)(v.z >> 16),
                (unsigned short)(v.w & 0xffff), (unsigned short)(v.w >> 16)};
            #pragma unroll
            for (int j = 0; j < 8; j++) VT_lds[(chunk + j) * 264 + rr] = vs[j];
        }
    }
    __syncthreads();

    const int w = tid >> 6, lane = tid & 63;
    const int l16 = lane & 15, quad = lane >> 4;
    const float* bmh = bm + (long)h * NPOS;
    unsigned short* P_w = &P_lds[w][0];
    const float scale = 0.17677669529663687f;   // 1/sqrt(32)

    #pragma unroll 1
    for (int i = 0; i < 4; i++) {
        const int q0 = (w * 4 + i) * 16;
        // Q B-frag: B[n=q=l16][k=d] — row q0+l16 of Q
        short8 bq = *(const short8*)(strip + (size_t)(bl * 256 + q0 + l16) * 512 + h * 32 + quad * 8);

        float sc[16][4];
        #pragma unroll
        for (int nt = 0; nt < 16; nt++) {
            // K A-frag: A[m=l16][k=d] — row nt*16+l16 of K
            short8 ka = *(const short8*)(strip + (size_t)(bl * 256 + nt * 16 + l16) * 512 + 128 + h * 32 + quad * 8);
            f32x4 c = (f32x4){0.f, 0.f, 0.f, 0.f};
            c = __builtin_amdgcn_mfma_f32_16x16x32_bf16(ka, bq, c, 0, 0, 0);
            // c[rr] = S[q=l16][key=nt*16+quad*4+rr]; bias contiguous -> float4
            float4 bs = *(const float4*)(bmh + (size_t)(q0 + l16) * 256 + nt * 16 + quad * 4);
            sc[nt][0] = c[0] * scale + bs.x;
            sc[nt][1] = c[1] * scale + bs.y;
            sc[nt][2] = c[2] * scale + bs.z;
            sc[nt][3] = c[3] * scale + bs.w;
        }
        // softmax over keys for q=l16: per-lane 64 + reduce across quads
        float mx = sc[0][0];
        #pragma unroll
        for (int nt = 0; nt < 16; nt++)
            #pragma unroll
            for (int rr = 0; rr < 4; rr++) mx = fmaxf(mx, sc[nt][rr]);
        mx = fmaxf(mx, __shfl_xor(mx, 16));
        mx = fmaxf(mx, __shfl_xor(mx, 32));
        float sm = 0.f;
        #pragma unroll
        for (int nt = 0; nt < 16; nt++)
            #pragma unroll
            for (int rr = 0; rr < 4; rr++) {
                float pv = __expf(sc[nt][rr] - mx);
                sc[nt][rr] = pv; sm += pv;
            }
        sm += __shfl_xor(sm, 16);
        sm += __shfl_xor(sm, 32);
        const float inv = 1.f / sm;

        f32x4 oacc[2];
        oacc[0] = (f32x4){0.f, 0.f, 0.f, 0.f};
        oacc[1] = (f32x4){0.f, 0.f, 0.f, 0.f};
        #pragma unroll
        for (int half = 0; half < 2; half++) {
            // write P half: P[q=l16][key(local) = t*16+quad*4 .. +3]
            #pragma unroll
            for (int t = 0; t < 8; t++) {
                int nt = half * 8 + t;
                s4b pk = { (short)f2b(sc[nt][0] * inv), (short)f2b(sc[nt][1] * inv),
                           (short)f2b(sc[nt][2] * inv), (short)f2b(sc[nt][3] * inv) };
                *(s4b*)(&P_w[l16 * 136 + t * 16 + quad * 4]) = pk;
            }
            // PV over this half's 128 keys
            #pragma unroll
            for (int kt = 0; kt < 4; kt++) {
                short8 pa = *(const short8*)(&P_w[l16 * 136 + kt * 32 + quad * 8]);
                #pragma unroll
                for (int nh = 0; nh < 2; nh++) {
                    short8 vb = *(const short8*)(&VT_lds[(nh * 16 + l16) * 264 + half * 128 + kt * 32 + quad * 8]);
                    oacc[nh] = __builtin_amdgcn_mfma_f32_16x16x32_bf16(pa, vb, oacc[nh], 0, 0, 0);
                }
            }
        }
        // epilogue: oacc C-layout row(q)=quad*4+rr, col(d)=l16; inv already folded
        #pragma unroll
        for (int rr = 0; rr < 4; rr++) {
            int row = q0 + quad * 4 + rr;
            #pragma unroll
            for (int nh = 0; nh < 2; nh++) {
                int cl = nh * 16 + l16;   // 0..31
                float g = b2f(strip[(size_t)(bl * 256 + row) * 512 + 384 + h * 32 + cl]);
                float ov = oacc[nh][rr] / (1.f + __expf(-g));
                out[((long)b * 256 + row) * 128 + h * 32 + cl] = ov;   // fp32
            }
        }
    }
}

// ---------------------------------------------------------------------------
// K4: output projection (MFMA), in-place on fp32 d_out.  As round 8.
// ---------------------------------------------------------------------------
__global__ __launch_bounds__(256) void outproj_mfma_kernel(
    const float* __restrict__ Wo, float* out)
{
    __shared__ __align__(16) unsigned short A_lds[64 * 136];
    __shared__ __align__(16) unsigned short W_lds[128 * 136];
    const int tid = threadIdx.x;
    const int m0 = blockIdx.x * 64;

    const int lr = tid >> 4, c8 = (tid & 15) * 8;
    #pragma unroll
    for (int i = 0; i < 4; i++) {
        const float* src = out + (size_t)(m0 + lr + i * 16) * 128 + c8;
        float4 f0 = *(const float4*)(src);
        float4 f1 = *(const float4*)(src + 4);
        unsigned short pk[8] = {f2b(f0.x), f2b(f0.y), f2b(f0.z), f2b(f0.w),
                                f2b(f1.x), f2b(f1.y), f2b(f1.z), f2b(f1.w)};
        *(uint4*)(&A_lds[(lr + i * 16) * 136 + c8]) = *(const uint4*)pk;
    }
    #pragma unroll
    for (int i = 0; i < 8; i++) {
        const float* src = Wo + (size_t)(lr + i * 16) * 128 + c8;
        float4 f0 = *(const float4*)(src);
        float4 f1 = *(const float4*)(src + 4);
        unsigned short pk[8] = {f2b(f0.x), f2b(f0.y), f2b(f0.z), f2b(f0.w),
                                f2b(f1.x), f2b(f1.y), f2b(f1.z), f2b(f1.w)};
        *(uint4*)(&W_lds[(lr + i * 16) * 136 + c8]) = *(const uint4*)pk;
    }
    __syncthreads();

    const int w = tid >> 6, lane = tid & 63;
    const int l16 = lane & 15, quad = lane >> 4;
    f32x4 acc[8];
    #pragma unroll
    for (int nt = 0; nt < 8; nt++) acc[nt] = (f32x4){0.f, 0.f, 0.f, 0.f};

    #pragma unroll
    for (int k0 = 0; k0 < 128; k0 += 32) {
        short8 a = *(const short8*)(&A_lds[(w * 16 + l16) * 136 + k0 + quad * 8]);
        #pragma unroll
        for (int nt = 0; nt < 8; nt++) {
            short8 b = *(const short8*)(&W_lds[(nt * 16 + l16) * 136 + k0 + quad * 8]);
            acc[nt] = __builtin_amdgcn_mfma_f32_16x16x32_bf16(a, b, acc[nt], 0, 0, 0);
        }
    }

    #pragma unroll
    for (int nt = 0; nt < 8; nt++)
        #pragma unroll
        for (int rr = 0; rr < 4; rr++) {
            int row = m0 + w * 16 + quad * 4 + rr;
            out[(size_t)row * 128 + nt * 16 + l16] = acc[nt][rr];   // fp32
        }
}

// ---------------------------------------------------------------------------
extern "C" void kernel_launch(void* const* d_in, const int* in_sizes, int n_in,
                              void* d_out, int out_size, void* d_ws, size_t ws_size,
                              hipStream_t stream)
{
    (void)in_sizes; (void)n_in; (void)out_size;
    const float* x    = (const float*)d_in[0];
    const float* mask = (const float*)d_in[1];
    const float* lnw  = (const float*)d_in[2];
    const float* lnb  = (const float*)d_in[3];
    const float* Wb   = (const float*)d_in[4];
    const float* Wq   = (const float*)d_in[5];
    const float* Wk   = (const float*)d_in[6];
    const float* Wv   = (const float*)d_in[7];
    const float* Wg   = (const float*)d_in[8];
    const float* Wo   = (const float*)d_in[9];
    float* out = (float*)d_out;   // fp32

    const size_t bmB = (size_t)H_DIM * NPOS * sizeof(float);   // 1 MB
    int HB = 256;
    while (HB > 16 && bmB + (size_t)HB * 256 * 512 * 2 > ws_size) HB >>= 1;

    char* ws = (char*)d_ws;
    float*          bm    = (float*)ws;
    unsigned short* strip = (unsigned short*)(ws + bmB);

    ln_biasmask_kernel<<<NPOS / 4, 256, 0, stream>>>(x, mask, lnw, lnb, Wb, bm);
    for (int b0 = 0; b0 < S_DIM; b0 += HB) {
        proj_ln_kernel<<<dim3(HB * 4, 4), 256, 0, stream>>>(
            x, lnw, lnb, Wq, Wk, Wv, Wg, b0 * 256, strip);
        attn_kernel<<<dim3(HB, H_DIM), 256, 0, stream>>>(strip, bm, b0, out);
    }
    outproj_mfma_kernel<<<NPOS / 64, 256, 0, stream>>>(Wo, out);
}